// Round 1
// baseline (9833.189 us; speedup 1.0000x reference)
//
#include <hip/hip_runtime.h>
#include <stdint.h>
#include <math.h>

// ---- problem constants ----
constexpr int HD     = 512;    // hidden/embed dim
constexpr int TSTEPS = 256;    // sequence length
constexpr int NBATCH = 64;     // batch per direction
constexpr int MB     = 128;    // fwd+rev batched rows
constexpr int NGATES = 2048;   // 4*HD
constexpr int KCOMB  = 1024;   // concat K: [x, h]

typedef __attribute__((ext_vector_type(8))) short bf16x8;
typedef __attribute__((ext_vector_type(4))) float f32x4;

__device__ __forceinline__ unsigned short f2bf(float f){
  union { float f; unsigned u; } v; v.f = f;
  unsigned r = v.u + 0x7fffu + ((v.u >> 16) & 1u);
  return (unsigned short)(r >> 16);
}
__device__ __forceinline__ float bf2f(unsigned short h){
  union { unsigned u; float f; } v; v.u = ((unsigned)h) << 16;
  return v.f;
}

// Build combined weight Wc[n][k] (bf16, row-major [NGATES][KCOMB]):
//   k <  HD : W_ih[n][k]
//   k >= HD : W_hh[n][k-HD]
__global__ void prep_w(const float* __restrict__ Wih, const float* __restrict__ Whh,
                       unsigned short* __restrict__ Wc){
  int idx = blockIdx.x * 256 + threadIdx.x;        // 0 .. NGATES*KCOMB-1
  int n = idx >> 10;
  int k = idx & (KCOMB - 1);
  float v = (k < HD) ? Wih[n * HD + k] : Whh[n * HD + (k - HD)];
  Wc[idx] = f2bf(v);
}

__global__ void prep_bias(const float* __restrict__ a, const float* __restrict__ b,
                          float* __restrict__ o){
  int i = blockIdx.x * 256 + threadIdx.x;
  if (i < NGATES) o[i] = a[i] + b[i];
}

// One LSTM timestep for one layer, fwd+rev batched (M = 128 rows).
// gates[M, 4H] = A1 @ Wih^T + Hprev @ Whh^T + bias   (as [A1,Hprev] @ Wc^T, K=1024)
// then cell update; h written as bf16 (and fp32 for layer 1).
// Grid: 128 WGs x 64 threads. WG = (m-tile of 32 rows) x (16 hidden units, all 4 gates).
template<bool LAYER0>
__global__ __launch_bounds__(64)
void lstm_step(const void* __restrict__ A1_, const unsigned short* __restrict__ Hprev,
               const unsigned short* __restrict__ Wc, const float* __restrict__ bias,
               float* __restrict__ Cst, unsigned short* __restrict__ Hout,
               float* __restrict__ HoutF, int t)
{
  const int l  = threadIdx.x;
  const int lr = l & 15;    // row (A) / col (B) within 16-tile
  const int lk = l >> 4;    // k-group: lane holds k = lk*8 .. lk*8+7
  const int j0 = (blockIdx.x & 31) * 16;   // hidden-unit slice
  const int m0 = (blockIdx.x >> 5) * 32;   // batch-row tile

  // B rows: gate g, hidden unit j0+lr  ->  Wc row n = g*HD + j0 + lr
  const unsigned short* brow[4];
  #pragma unroll
  for (int g = 0; g < 4; ++g)
    brow[g] = Wc + (size_t)(g * HD + j0 + lr) * KCOMB + lk * 8;

  const float*          a1f[2];
  const unsigned short* a1b[2];
  const unsigned short* hrow[2];
  #pragma unroll
  for (int mi = 0; mi < 2; ++mi){
    int row = m0 + mi * 16 + lr;
    if constexpr (LAYER0){
      const float* text = (const float*)A1_;
      int bb = (row < NBATCH) ? row : row - NBATCH;
      int tt = (row < NBATCH) ? t   : (TSTEPS - 1 - t);   // reverse direction reads flipped time
      a1f[mi] = text + ((size_t)bb * TSTEPS + tt) * HD;
    } else {
      a1b[mi] = (const unsigned short*)A1_ + (size_t)row * HD;
    }
    hrow[mi] = Hprev + (size_t)row * HD;
  }

  f32x4 acc[2][4] = {};   // [m-frag][gate]

  // ---- K half 1: input piece (k = 0..511 of Wc rows) ----
  for (int kk = 0; kk < 16; ++kk){
    const int ke = kk * 32 + lk * 8;
    bf16x8 bfr[4], afr[2];
    #pragma unroll
    for (int g = 0; g < 4; ++g)
      bfr[g] = *(const bf16x8*)(brow[g] + kk * 32);
    #pragma unroll
    for (int mi = 0; mi < 2; ++mi){
      if constexpr (LAYER0){
        const float* p = a1f[mi] + ke;
        float4 v0 = ((const float4*)p)[0];
        float4 v1 = ((const float4*)p)[1];
        bf16x8 a;
        a[0] = (short)f2bf(v0.x); a[1] = (short)f2bf(v0.y);
        a[2] = (short)f2bf(v0.z); a[3] = (short)f2bf(v0.w);
        a[4] = (short)f2bf(v1.x); a[5] = (short)f2bf(v1.y);
        a[6] = (short)f2bf(v1.z); a[7] = (short)f2bf(v1.w);
        afr[mi] = a;
      } else {
        afr[mi] = *(const bf16x8*)(a1b[mi] + ke);
      }
    }
    #pragma unroll
    for (int mi = 0; mi < 2; ++mi)
      #pragma unroll
      for (int g = 0; g < 4; ++g)
        acc[mi][g] = __builtin_amdgcn_mfma_f32_16x16x32_bf16(afr[mi], bfr[g], acc[mi][g], 0, 0, 0);
  }

  // ---- K half 2: recurrent piece (k = 512..1023 of Wc rows) ----
  for (int kk = 0; kk < 16; ++kk){
    const int ke = kk * 32 + lk * 8;
    bf16x8 bfr[4], afr[2];
    #pragma unroll
    for (int g = 0; g < 4; ++g)
      bfr[g] = *(const bf16x8*)(brow[g] + HD + kk * 32);
    #pragma unroll
    for (int mi = 0; mi < 2; ++mi)
      afr[mi] = *(const bf16x8*)(hrow[mi] + ke);
    #pragma unroll
    for (int mi = 0; mi < 2; ++mi)
      #pragma unroll
      for (int g = 0; g < 4; ++g)
        acc[mi][g] = __builtin_amdgcn_mfma_f32_16x16x32_bf16(afr[mi], bfr[g], acc[mi][g], 0, 0, 0);
  }

  // ---- cell update ----
  // C/D layout (verified m89): col = lane&15, row = (lane>>4)*4 + reg
  const int jj = j0 + lr;
  const float bi = bias[0 * HD + jj];
  const float bf = bias[1 * HD + jj];
  const float bg = bias[2 * HD + jj];
  const float bo = bias[3 * HD + jj];
  #pragma unroll
  for (int mi = 0; mi < 2; ++mi){
    #pragma unroll
    for (int r = 0; r < 4; ++r){
      int brw = m0 + mi * 16 + lk * 4 + r;
      size_t cidx = (size_t)brw * HD + jj;
      float gi = acc[mi][0][r] + bi;
      float gf = acc[mi][1][r] + bf;
      float gg = acc[mi][2][r] + bg;
      float go = acc[mi][3][r] + bo;
      float i_ = 1.f / (1.f + expf(-gi));
      float f_ = 1.f / (1.f + expf(-gf));
      float g_ = tanhf(gg);
      float o_ = 1.f / (1.f + expf(-go));
      float c  = f_ * Cst[cidx] + i_ * g_;
      Cst[cidx] = c;
      float h = o_ * tanhf(c);
      Hout[cidx] = f2bf(h);
      if constexpr (!LAYER0) HoutF[cidx] = h;
    }
  }
}

// out[b] = dot(h1_fwd[b], Wlin[0:512]) + dot(h1_rev[b], Wlin[512:1024]) + blin
__global__ void final_linear(const float* __restrict__ H1f, const float* __restrict__ Wlin,
                             const float* __restrict__ blin, float* __restrict__ out){
  int b = blockIdx.x, l = threadIdx.x;   // 64 blocks x 64 threads
  float s = 0.f;
  for (int j = l; j < HD; j += 64) s += H1f[(size_t)b * HD + j]            * Wlin[j];
  for (int j = l; j < HD; j += 64) s += H1f[(size_t)(NBATCH + b) * HD + j] * Wlin[HD + j];
  #pragma unroll
  for (int off = 32; off; off >>= 1) s += __shfl_down(s, off);
  if (l == 0) out[b] = s + blin[0];
}

extern "C" void kernel_launch(void* const* d_in, const int* in_sizes, int n_in,
                              void* d_out, int out_size, void* d_ws, size_t ws_size,
                              hipStream_t stream)
{
  const float* text = (const float*)d_in[0];
  const float* Wih0 = (const float*)d_in[1];
  const float* Whh0 = (const float*)d_in[2];
  const float* bih0 = (const float*)d_in[3];
  const float* bhh0 = (const float*)d_in[4];
  const float* Wih1 = (const float*)d_in[5];
  const float* Whh1 = (const float*)d_in[6];
  const float* bih1 = (const float*)d_in[7];
  const float* bhh1 = (const float*)d_in[8];
  const float* Wlin = (const float*)d_in[9];
  const float* blin = (const float*)d_in[10];

  // ---- ws layout ----
  uint8_t* p = (uint8_t*)d_ws;
  unsigned short* Wc0 = (unsigned short*)p;  p += (size_t)NGATES * KCOMB * 2;  // 4 MiB
  unsigned short* Wc1 = (unsigned short*)p;  p += (size_t)NGATES * KCOMB * 2;  // 4 MiB
  float* bias0 = (float*)p;  p += (size_t)NGATES * 4;
  float* bias1 = (float*)p;  p += (size_t)NGATES * 4;
  uint8_t* zstart = p;
  unsigned short* zeroH = (unsigned short*)p;  p += (size_t)MB * HD * 2;       // 128 KiB (stays 0)
  float* c0 = (float*)p;  p += (size_t)MB * HD * 4;                            // 256 KiB
  float* c1 = (float*)p;  p += (size_t)MB * HD * 4;                            // 256 KiB
  size_t zbytes = (size_t)(p - zstart);
  unsigned short* H0seq = (unsigned short*)p;  p += (size_t)TSTEPS * MB * HD * 2; // 32 MiB
  unsigned short* H1r   = (unsigned short*)p;  p += (size_t)2 * MB * HD * 2;      // ring, bf16
  float*          H1f   = (float*)p;           p += (size_t)2 * MB * HD * 4;      // ring, fp32

  const int SL = MB * HD;  // 65536 elems per timestep slab

  // deterministic init every call (ws is poisoned once, never re-poisoned)
  hipMemsetAsync(zstart, 0, zbytes, stream);
  prep_w<<<(NGATES * KCOMB) / 256, 256, 0, stream>>>(Wih0, Whh0, Wc0);
  prep_w<<<(NGATES * KCOMB) / 256, 256, 0, stream>>>(Wih1, Whh1, Wc1);
  prep_bias<<<NGATES / 256, 256, 0, stream>>>(bih0, bhh0, bias0);
  prep_bias<<<NGATES / 256, 256, 0, stream>>>(bih1, bhh1, bias1);

  // layer 0: both directions batched, writes full hidden sequence
  for (int t = 0; t < TSTEPS; ++t){
    const unsigned short* hp = t ? (H0seq + (size_t)(t - 1) * SL) : zeroH;
    lstm_step<true><<<128, 64, 0, stream>>>(text, hp, Wc0, bias0, c0,
                                            H0seq + (size_t)t * SL, nullptr, t);
  }
  // layer 1: consumes h0 sequence, 2-slot ring for its own state
  for (int t = 0; t < TSTEPS; ++t){
    const unsigned short* hp = t ? (H1r + (size_t)((t - 1) & 1) * SL) : zeroH;
    lstm_step<false><<<128, 64, 0, stream>>>(H0seq + (size_t)t * SL, hp, Wc1, bias1, c1,
                                             H1r + (size_t)(t & 1) * SL,
                                             H1f + (size_t)(t & 1) * SL, t);
  }
  // final slot for t = 255 is (255 & 1) = 1
  final_linear<<<NBATCH, 64, 0, stream>>>(H1f + (size_t)1 * SL, Wlin, blin, (float*)d_out);
}

// Round 2
// 9270.454 us; speedup vs baseline: 1.0607x; 1.0607x over previous
//
#include <hip/hip_runtime.h>
#include <hip/hip_cooperative_groups.h>
#include <stdint.h>
#include <math.h>

namespace cg = cooperative_groups;

// ---- problem constants ----
constexpr int HD   = 512;    // hidden/embed dim
constexpr int TS   = 256;    // sequence length
constexpr int NB   = 64;     // batch per direction
constexpr int MBR  = 128;    // fwd+rev batched rows
constexpr int SLAB = MBR * HD;  // 65536 elements per h-slab

typedef __attribute__((ext_vector_type(8))) short bf16x8;
typedef __attribute__((ext_vector_type(4))) float f32x4;

__device__ __forceinline__ unsigned short f2bf(float f){
  union { float f; unsigned u; } v; v.f = f;
  unsigned r = v.u + 0x7fffu + ((v.u >> 16) & 1u);
  return (unsigned short)(r >> 16);
}

__device__ __forceinline__ float fsig(float x){ return 1.f / (1.f + __expf(-x)); }
__device__ __forceinline__ float ftanh(float x){ return 1.f - 2.f / (__expf(2.f * x) + 1.f); }

// Wc[n][k] bf16 (row-major [2048][1024]): k<512 -> Wih[n][k], k>=512 -> Whh[n][k-512]
__global__ void prep_w(const float* __restrict__ Wih, const float* __restrict__ Whh,
                       unsigned short* __restrict__ Wc){
  int idx = blockIdx.x * 256 + threadIdx.x;
  int n = idx >> 10;
  int k = idx & 1023;
  float v = (k < HD) ? Wih[n * HD + k] : Whh[n * HD + (k - HD)];
  Wc[idx] = f2bf(v);
}

__global__ void prep_bias(const float* __restrict__ a, const float* __restrict__ b,
                          float* __restrict__ o){
  int i = blockIdx.x * 256 + threadIdx.x;
  if (i < 2048) o[i] = a[i] + b[i];
}

// Xp[t][row][k] bf16: row<64: text[row][t][k]; row>=64: text[row-64][TS-1-t][k]
__global__ void pack_x(const float* __restrict__ text, unsigned short* __restrict__ Xp){
  int idx = blockIdx.x * 256 + threadIdx.x;   // TS*MBR*HD = 16,777,216
  int k   = idx & 511;
  int row = (idx >> 9) & 127;
  int t   = idx >> 16;
  int b   = row & 63;
  int tt  = (row < 64) ? t : (TS - 1 - t);
  Xp[idx] = f2bf(text[((size_t)b * TS + tt) * HD + k]);
}

// Persistent pipelined 2-layer LSTM.
// Grid: 256 WGs x 512 threads (8 waves), 1 WG/CU, 128 KB LDS.
// WG wg: layer = wg>>7; wl = wg&127; m-tile m0 = (wl>>5)*32 (32 rows);
//        unit-slice u0 = (wl&31)*16 (16 units x 4 gates = 64 gate-cols).
// Wave wv (0..7): col-group wgrp = wv&3 (16 cols), m-frag mi = wv>>2 (16 rows).
// Grid step s: L0 computes t=s (s<TS), L1 computes t=s-1 (s>=1); both read h0[s-1].
__global__ __launch_bounds__(512, 1)
void lstm_persist(const unsigned short* __restrict__ Xp,
                  const unsigned short* __restrict__ Wc,   // [2][2048][1024] bf16
                  const float* __restrict__ bias,          // [2][2048]
                  unsigned short* __restrict__ h0r,        // [2][128][512] bf16 ring
                  unsigned short* __restrict__ h1r,        // [2][128][512] bf16 ring
                  float* __restrict__ H1f)                 // [128][512] fp32 (final h1)
{
  extern __shared__ unsigned short Blds[];   // 64 cols x 1024 k, XOR-swizzled, 128 KB

  const int wg    = blockIdx.x;
  const int layer = wg >> 7;
  const int wl    = wg & 127;
  const int m0    = (wl >> 5) * 32;
  const int u0    = (wl & 31) * 16;
  const int tid   = threadIdx.x;
  const int wv    = tid >> 6;
  const int l     = tid & 63;
  const int lj    = l & 15;
  const int lk    = l >> 4;
  const int wgrp  = wv & 3;
  const int mi    = wv >> 2;

  const unsigned short* Wcl = Wc + (size_t)layer * 2048 * 1024;
  const float* bl = bias + layer * 2048;

  // ---- one-time: stage this WG's weight slice into LDS, swizzled ----
  // col c (0..63): unit = u0 + (c>>4)*4 + ((c&15)>>2), gate = c&3 -> Wc row n = gate*512+unit
  // granule kg (0..127) of 8 bf16; LDS byte = c*2048 + ((kg ^ (c&7))<<4)
  for (int it = tid; it < 64 * 128; it += 512){
    int c  = it >> 7, kg = it & 127;
    int unit = u0 + ((c >> 4) << 2) + ((c & 15) >> 2);
    int gate = c & 3;
    bf16x8 v = *(const bf16x8*)(Wcl + (size_t)(gate * HD + unit) * 1024 + kg * 8);
    *(bf16x8*)((char*)Blds + c * 2048 + ((kg ^ (c & 7)) << 4)) = v;
  }

  const int myunit = u0 + (wgrp << 2) + (lj >> 2);
  const int mygate = lj & 3;
  const float bgv  = bl[mygate * HD + myunit];

  const int aoff = (m0 + mi * 16 + lj) * HD + lk * 8;  // A-row element offset
  const int cboff = (wgrp * 16 + lj) * 2048;           // B col byte base in LDS
  const int swz  = lj & 7;

  float cst[4] = {0.f, 0.f, 0.f, 0.f};   // cell state (row = m0+mi*16+lk*4+r, unit = myunit)

  cg::grid_group grid = cg::this_grid();
  __syncthreads();   // B slice ready

  for (int s = 0; s <= TS; ++s){
    const bool act = (layer == 0) ? (s < TS) : (s >= 1);
    if (act){
      const unsigned short* s0;   // k = 0..511 source rows
      const unsigned short* s1;   // k = 512..1023 source rows
      unsigned short* hout;
      if (layer == 0){
        s0 = Xp + (size_t)s * SLAB;
        s1 = h0r + (size_t)((s - 1) & 1) * SLAB;
        hout = h0r + (size_t)(s & 1) * SLAB;
      } else {
        s0 = h0r + (size_t)((s - 1) & 1) * SLAB;
        s1 = h1r + (size_t)(s & 1) * SLAB;          // h1[s-2]: slot (s-2)&1 == s&1
        hout = h1r + (size_t)((s - 1) & 1) * SLAB;  // writes h1[s-1]
      }

      f32x4 acc = {0.f, 0.f, 0.f, 0.f};
      #pragma unroll
      for (int kk = 0; kk < 16; ++kk){
        bf16x8 bfr = *(const bf16x8*)((const char*)Blds + cboff + (((kk * 4 + lk) ^ swz) << 4));
        bf16x8 a   = *(const bf16x8*)(s0 + aoff + kk * 32);
        acc = __builtin_amdgcn_mfma_f32_16x16x32_bf16(a, bfr, acc, 0, 0, 0);
      }
      #pragma unroll
      for (int kk = 0; kk < 16; ++kk){
        bf16x8 bfr = *(const bf16x8*)((const char*)Blds + cboff + ((((kk + 16) * 4 + lk) ^ swz) << 4));
        bf16x8 a   = *(const bf16x8*)(s1 + aoff + kk * 32);
        acc = __builtin_amdgcn_mfma_f32_16x16x32_bf16(a, bfr, acc, 0, 0, 0);
      }

      // ---- cell update: gather 4 gates across the lane-quad via DPP shuffles ----
      const bool wrF = (layer == 1) && (s == TS);
      #pragma unroll
      for (int r = 0; r < 4; ++r){
        float v  = acc[r] + bgv;
        float v1 = __shfl_xor(v, 1);
        float v2 = __shfl_xor(v, 2);
        float v3 = __shfl_xor(v, 3);
        auto pick = [&](int m)->float {
          return m == 0 ? v : (m == 1 ? v1 : (m == 2 ? v2 : v3));
        };
        float gi = pick(mygate);
        float gf = pick(mygate ^ 1);
        float gg = pick(mygate ^ 2);
        float go = pick(mygate ^ 3);
        float i_ = fsig(gi);
        float f_ = fsig(gf);
        float g_ = ftanh(gg);
        float o_ = fsig(go);
        float c  = f_ * cst[r] + i_ * g_;
        cst[r] = c;
        float h = o_ * ftanh(c);
        if (mygate == 0){
          int row = m0 + mi * 16 + lk * 4 + r;
          hout[(size_t)row * HD + myunit] = f2bf(h);
          if (wrF) H1f[(size_t)row * HD + myunit] = h;
        }
      }
    }
    grid.sync();
  }
}

// out[b] = dot(h1_fwd[b], Wlin[0:512]) + dot(h1_rev[b], Wlin[512:1024]) + blin
__global__ void final_linear(const float* __restrict__ H1f, const float* __restrict__ Wlin,
                             const float* __restrict__ blin, float* __restrict__ out){
  int b = blockIdx.x, l = threadIdx.x;
  float s = 0.f;
  for (int j = l; j < HD; j += 64) s += H1f[(size_t)b * HD + j]        * Wlin[j];
  for (int j = l; j < HD; j += 64) s += H1f[(size_t)(NB + b) * HD + j] * Wlin[HD + j];
  #pragma unroll
  for (int off = 32; off; off >>= 1) s += __shfl_down(s, off);
  if (l == 0) out[b] = s + blin[0];
}

extern "C" void kernel_launch(void* const* d_in, const int* in_sizes, int n_in,
                              void* d_out, int out_size, void* d_ws, size_t ws_size,
                              hipStream_t stream)
{
  const float* text = (const float*)d_in[0];
  const float* Wih0 = (const float*)d_in[1];
  const float* Whh0 = (const float*)d_in[2];
  const float* bih0 = (const float*)d_in[3];
  const float* bhh0 = (const float*)d_in[4];
  const float* Wih1 = (const float*)d_in[5];
  const float* Whh1 = (const float*)d_in[6];
  const float* bih1 = (const float*)d_in[7];
  const float* bhh1 = (const float*)d_in[8];
  const float* Wlin = (const float*)d_in[9];
  const float* blin = (const float*)d_in[10];

  // ---- ws layout (~41 MiB, same footprint class as round 1 which fit) ----
  uint8_t* p = (uint8_t*)d_ws;
  unsigned short* Wc  = (unsigned short*)p; p += (size_t)2 * 2048 * 1024 * 2;  // 8 MiB
  float* bias         = (float*)p;          p += (size_t)2 * 2048 * 4;         // 16 KiB
  unsigned short* Xp  = (unsigned short*)p; p += (size_t)TS * SLAB * 2;        // 32 MiB
  unsigned short* h0r = (unsigned short*)p; p += (size_t)2 * SLAB * 2;         // 256 KiB
  unsigned short* h1r = (unsigned short*)p; p += (size_t)2 * SLAB * 2;         // 256 KiB
  float* H1f          = (float*)p;          p += (size_t)SLAB * 4;             // 256 KiB

  // deterministic init every call: zero both h rings (contiguous 512 KiB)
  hipMemsetAsync(h0r, 0, (size_t)4 * SLAB * 2, stream);

  prep_w<<<8192, 256, 0, stream>>>(Wih0, Whh0, Wc);
  prep_w<<<8192, 256, 0, stream>>>(Wih1, Whh1, Wc + (size_t)2048 * 1024);
  prep_bias<<<8, 256, 0, stream>>>(bih0, bhh0, bias);
  prep_bias<<<8, 256, 0, stream>>>(bih1, bhh1, bias + 2048);
  pack_x<<<65536, 256, 0, stream>>>(text, Xp);

  hipFuncSetAttribute((const void*)lstm_persist,
                      hipFuncAttributeMaxDynamicSharedMemorySize, 131072);

  const unsigned short* XpA = Xp;
  const unsigned short* WcA = Wc;
  const float* biasA = bias;
  unsigned short* h0A = h0r;
  unsigned short* h1A = h1r;
  float* H1fA = H1f;
  void* args[] = {(void*)&XpA, (void*)&WcA, (void*)&biasA,
                  (void*)&h0A, (void*)&h1A, (void*)&H1fA};
  hipLaunchCooperativeKernel((void*)lstm_persist, dim3(256), dim3(512),
                             args, 131072, stream);

  final_linear<<<NB, 64, 0, stream>>>(H1f, Wlin, blin, (float*)d_out);
}

// Round 3
// 4179.394 us; speedup vs baseline: 2.3528x; 2.2181x over previous
//
#include <hip/hip_runtime.h>
#include <stdint.h>
#include <math.h>

// ---- problem constants ----
constexpr int HD   = 512;    // hidden/embed dim
constexpr int TS   = 256;    // sequence length
constexpr int NB   = 64;     // batch per direction
constexpr int MBR  = 128;    // fwd+rev batched rows
constexpr int SLAB = MBR * HD;  // 65536 elements per h-slab
constexpr int NSTEP = TS + 2;   // pipeline: L0 t=s (s=0..255), L1 t=s-2 (s=2..257)

typedef __attribute__((ext_vector_type(8))) short bf16x8;
typedef __attribute__((ext_vector_type(4))) float f32x4;

__device__ __forceinline__ unsigned short f2bf(float f){
  union { float f; unsigned u; } v; v.f = f;
  unsigned r = v.u + 0x7fffu + ((v.u >> 16) & 1u);
  return (unsigned short)(r >> 16);
}
__device__ __forceinline__ float fsig(float x){ return 1.f / (1.f + __expf(-x)); }
__device__ __forceinline__ float ftanh(float x){ return 1.f - 2.f / (__expf(2.f * x) + 1.f); }

// Wc[n][k] bf16 (row-major [2048][1024]): k<512 -> Wih[n][k], k>=512 -> Whh[n][k-512]
__global__ void prep_w(const float* __restrict__ Wih, const float* __restrict__ Whh,
                       unsigned short* __restrict__ Wc){
  int idx = blockIdx.x * 256 + threadIdx.x;
  int n = idx >> 10;
  int k = idx & 1023;
  float v = (k < HD) ? Wih[n * HD + k] : Whh[n * HD + (k - HD)];
  Wc[idx] = f2bf(v);
}

__global__ void prep_bias(const float* __restrict__ a, const float* __restrict__ b,
                          float* __restrict__ o){
  int i = blockIdx.x * 256 + threadIdx.x;
  if (i < 2048) o[i] = a[i] + b[i];
}

// Xp[t][row][k] bf16: row<64: text[row][t][k]; row>=64: text[row-64][TS-1-t][k]
__global__ void pack_x(const float* __restrict__ text, unsigned short* __restrict__ Xp){
  int idx = blockIdx.x * 256 + threadIdx.x;   // TS*MBR*HD = 16,777,216
  int k   = idx & 511;
  int row = (idx >> 9) & 127;
  int t   = idx >> 16;
  int b   = row & 63;
  int tt  = (row < 64) ? t : (TS - 1 - t);
  Xp[idx] = f2bf(text[((size_t)b * TS + tt) * HD + k]);
}

// Persistent pipelined 2-layer LSTM with per-m-tile dataflow barriers.
// Grid: 256 WGs x 512 threads, 1 WG/CU, 128 KB LDS.
// WG wg: layer = wg>>7; wl = wg&127; group grp = wl>>5 (32 batch rows, both layers
//        of one group form a 64-WG dependency set); unit-slice u0 = (wl&31)*16.
// Wave wv: col-group wgrp = wv&3 (16 gate-cols), m-frag mi = wv>>2 (16 rows).
// Step s: L0 computes t=s; L1 computes t=s-2.
// Per step: wait(cnt >= s*64) -> post-half (own recurrence, 16 MFMA) -> cell update
//           -> write h -> arrive(cnt++) -> pre-half for next step (input proj, 16 MFMA).
__global__ __launch_bounds__(512, 1)
void lstm_persist(const unsigned short* __restrict__ Xp,
                  const unsigned short* __restrict__ Wc,   // [2][2048][1024] bf16
                  const float* __restrict__ bias,          // [2][2048]
                  unsigned short* __restrict__ h0r,        // [4][128][512] bf16 ring
                  unsigned short* __restrict__ h1r,        // [2][128][512] bf16 ring
                  float* __restrict__ H1f,                 // [128][512] fp32 (final h1)
                  unsigned* __restrict__ cnt)              // [4][64] group counters
{
  extern __shared__ unsigned short Blds[];   // 64 cols x 1024 k, XOR-swizzled, 128 KB

  const int wg    = blockIdx.x;
  const int layer = wg >> 7;
  const int wl    = wg & 127;
  const int grp   = wl >> 5;
  const int m0    = grp * 32;
  const int u0    = (wl & 31) * 16;
  const int tid   = threadIdx.x;
  const int wv    = tid >> 6;
  const int l     = tid & 63;
  const int lj    = l & 15;
  const int lk    = l >> 4;
  const int wgrp  = wv & 3;
  const int mi    = wv >> 2;

  // ---- one-time: stage this WG's weight slice into LDS, swizzled ----
  const unsigned short* Wcl = Wc + (size_t)layer * 2048 * 1024;
  for (int it = tid; it < 64 * 128; it += 512){
    int c  = it >> 7, kg = it & 127;
    int unit = u0 + ((c >> 4) << 2) + ((c & 15) >> 2);
    int gate = c & 3;
    bf16x8 v = *(const bf16x8*)(Wcl + (size_t)(gate * HD + unit) * 1024 + kg * 8);
    *(bf16x8*)((char*)Blds + c * 2048 + ((kg ^ (c & 7)) << 4)) = v;
  }

  const int myunit = u0 + (wgrp << 2) + (lj >> 2);
  const int mygate = lj & 3;
  const float bgv  = bias[layer * 2048 + mygate * HD + myunit];
  const int aoff   = (m0 + mi * 16 + lj) * HD + lk * 8;
  const int cboff  = (wgrp * 16 + lj) * 2048;
  const int swz    = lj & 7;
  unsigned* mycnt  = cnt + grp * 64;   // one cacheline per group

  float cst[4] = {0.f, 0.f, 0.f, 0.f};
  __syncthreads();   // weights staged

  // 16-MFMA half-K accumulation: gb=0 -> input weights, gb=64 -> recurrent weights
  auto halfK = [&](const unsigned short* __restrict__ src, int gb, f32x4& acc){
    #pragma unroll
    for (int kk = 0; kk < 16; ++kk){
      bf16x8 b = *(const bf16x8*)((const char*)Blds + cboff + (((gb + kk * 4 + lk) ^ swz) << 4));
      bf16x8 a = *(const bf16x8*)(src + aoff + kk * 32);
      acc = __builtin_amdgcn_mfma_f32_16x16x32_bf16(a, b, acc, 0, 0, 0);
    }
  };

  // initial pre-half: L0's accX[0] (L1 has nothing yet)
  f32x4 accPre = {0.f, 0.f, 0.f, 0.f};
  if (layer == 0) halfK(Xp, 0, accPre);

  for (int s = 0; s < NSTEP; ++s){
    // ---- (A) wait: everything written in step s-1 becomes visible ----
    if (tid == 0){
      const unsigned tgt = (unsigned)s * 64u;
      while (__hip_atomic_load(mycnt, __ATOMIC_RELAXED, __HIP_MEMORY_SCOPE_AGENT) < tgt)
        __builtin_amdgcn_s_sleep(1);
      __builtin_amdgcn_fence(__ATOMIC_ACQUIRE, "agent");
    }
    __syncthreads();

    // ---- (B) post-half + cell update + h write ----
    const int t = (layer == 0) ? s : s - 2;
    if (t >= 0 && t < TS){
      f32x4 accPost = {0.f, 0.f, 0.f, 0.f};
      if (layer == 0){
        if (t > 0) halfK(h0r + (size_t)((t - 1) & 3) * SLAB, 64, accPost);
      } else {
        if (t > 0) halfK(h1r + (size_t)((t - 1) & 1) * SLAB, 64, accPost);
      }
      unsigned short* hout = (layer == 0) ? h0r + (size_t)(t & 3) * SLAB
                                          : h1r + (size_t)(t & 1) * SLAB;
      const bool wrF = (layer == 1) && (t == TS - 1);
      #pragma unroll
      for (int r = 0; r < 4; ++r){
        float v  = accPre[r] + accPost[r] + bgv;
        float v1 = __shfl_xor(v, 1);
        float v2 = __shfl_xor(v, 2);
        float v3 = __shfl_xor(v, 3);
        auto pick = [&](int m)->float {
          return m == 0 ? v : (m == 1 ? v1 : (m == 2 ? v2 : v3));
        };
        float gi = pick(mygate);
        float gf = pick(mygate ^ 1);
        float gg = pick(mygate ^ 2);
        float go = pick(mygate ^ 3);
        float i_ = fsig(gi);
        float f_ = fsig(gf);
        float g_ = ftanh(gg);
        float o_ = fsig(go);
        float c  = f_ * cst[r] + i_ * g_;
        cst[r] = c;
        float h = o_ * ftanh(c);
        if (mygate == 0){
          int row = m0 + mi * 16 + lk * 4 + r;
          hout[(size_t)row * HD + myunit] = f2bf(h);
          if (wrF) H1f[(size_t)row * HD + myunit] = h;
        }
      }
    }
    __syncthreads();   // drains all waves' h stores (compiler emits vmcnt(0) before barrier)

    // ---- (C) arrive: publish h writes of step s ----
    if (tid == 0)
      __hip_atomic_fetch_add(mycnt, 1u, __ATOMIC_RELEASE, __HIP_MEMORY_SCOPE_AGENT);

    // ---- (D) pre-half for next step, overlaps other WGs' arrival ----
    accPre = (f32x4){0.f, 0.f, 0.f, 0.f};
    if (layer == 0){
      const int tn = s + 1;                 // next t for L0
      if (tn < TS) halfK(Xp + (size_t)tn * SLAB, 0, accPre);
    } else {
      const int tn = s - 1;                 // next t for L1; reads h0[tn], visible since (A)
      if (tn >= 0 && tn < TS) halfK(h0r + (size_t)(tn & 3) * SLAB, 0, accPre);
    }
  }
}

// out[b] = dot(h1_fwd[b], Wlin[0:512]) + dot(h1_rev[b], Wlin[512:1024]) + blin
__global__ void final_linear(const float* __restrict__ H1f, const float* __restrict__ Wlin,
                             const float* __restrict__ blin, float* __restrict__ out){
  int b = blockIdx.x, l = threadIdx.x;
  float s = 0.f;
  for (int j = l; j < HD; j += 64) s += H1f[(size_t)b * HD + j]        * Wlin[j];
  for (int j = l; j < HD; j += 64) s += H1f[(size_t)(NB + b) * HD + j] * Wlin[HD + j];
  #pragma unroll
  for (int off = 32; off; off >>= 1) s += __shfl_down(s, off);
  if (l == 0) out[b] = s + blin[0];
}

extern "C" void kernel_launch(void* const* d_in, const int* in_sizes, int n_in,
                              void* d_out, int out_size, void* d_ws, size_t ws_size,
                              hipStream_t stream)
{
  const float* text = (const float*)d_in[0];
  const float* Wih0 = (const float*)d_in[1];
  const float* Whh0 = (const float*)d_in[2];
  const float* bih0 = (const float*)d_in[3];
  const float* bhh0 = (const float*)d_in[4];
  const float* Wih1 = (const float*)d_in[5];
  const float* Whh1 = (const float*)d_in[6];
  const float* bih1 = (const float*)d_in[7];
  const float* bhh1 = (const float*)d_in[8];
  const float* Wlin = (const float*)d_in[9];
  const float* blin = (const float*)d_in[10];

  // ---- ws layout (~42 MiB) ----
  uint8_t* p = (uint8_t*)d_ws;
  unsigned short* Wc  = (unsigned short*)p; p += (size_t)2 * 2048 * 1024 * 2;  // 8 MiB
  float* bias         = (float*)p;          p += (size_t)2 * 2048 * 4;         // 16 KiB
  unsigned short* Xp  = (unsigned short*)p; p += (size_t)TS * SLAB * 2;        // 32 MiB
  unsigned short* h0r = (unsigned short*)p; p += (size_t)4 * SLAB * 2;         // 512 KiB
  unsigned short* h1r = (unsigned short*)p; p += (size_t)2 * SLAB * 2;         // 256 KiB
  float* H1f          = (float*)p;          p += (size_t)SLAB * 4;             // 256 KiB
  unsigned* cnt       = (unsigned*)p;       p += (size_t)4 * 64 * 4;           // 1 KiB

  // deterministic init every call: counters MUST be zero at kernel start
  hipMemsetAsync(cnt, 0, (size_t)4 * 64 * 4, stream);

  prep_w<<<8192, 256, 0, stream>>>(Wih0, Whh0, Wc);
  prep_w<<<8192, 256, 0, stream>>>(Wih1, Whh1, Wc + (size_t)2048 * 1024);
  prep_bias<<<8, 256, 0, stream>>>(bih0, bhh0, bias);
  prep_bias<<<8, 256, 0, stream>>>(bih1, bhh1, bias + 2048);
  pack_x<<<65536, 256, 0, stream>>>(text, Xp);

  hipFuncSetAttribute((const void*)lstm_persist,
                      hipFuncAttributeMaxDynamicSharedMemorySize, 131072);

  const unsigned short* XpA = Xp;
  const unsigned short* WcA = Wc;
  const float* biasA = bias;
  unsigned short* h0A = h0r;
  unsigned short* h1A = h1r;
  float* H1fA = H1f;
  unsigned* cntA = cnt;
  void* args[] = {(void*)&XpA, (void*)&WcA, (void*)&biasA,
                  (void*)&h0A, (void*)&h1A, (void*)&H1fA, (void*)&cntA};
  hipLaunchCooperativeKernel((void*)lstm_persist, dim3(256), dim3(512),
                             args, 131072, stream);

  final_linear<<<NB, 64, 0, stream>>>(H1f, Wlin, blin, (float*)d_out);
}

// Round 4
// 4029.802 us; speedup vs baseline: 2.4401x; 1.0371x over previous
//
#include <hip/hip_runtime.h>
#include <stdint.h>
#include <math.h>

// ---- problem constants ----
constexpr int HD   = 512;    // hidden/embed dim
constexpr int TS   = 256;    // sequence length
constexpr int NB   = 64;     // batch per direction
constexpr int MBR  = 128;    // fwd+rev batched rows
constexpr int SLAB = MBR * HD;  // 65536 elements per h-slab

typedef __attribute__((ext_vector_type(8))) short bf16x8;
typedef __attribute__((ext_vector_type(4))) float f32x4;

__device__ __forceinline__ unsigned short f2bf(float f){
  union { float f; unsigned u; } v; v.f = f;
  unsigned r = v.u + 0x7fffu + ((v.u >> 16) & 1u);
  return (unsigned short)(r >> 16);
}
__device__ __forceinline__ float fsig(float x){ return 1.f / (1.f + __expf(-x)); }
__device__ __forceinline__ float ftanh(float x){ return 1.f - 2.f / (__expf(2.f * x) + 1.f); }

// Wc[n][k] bf16 (row-major [2048][1024]): k<512 -> Wih[n][k], k>=512 -> Whh[n][k-512]
__global__ void prep_w(const float* __restrict__ Wih, const float* __restrict__ Whh,
                       unsigned short* __restrict__ Wc){
  int idx = blockIdx.x * 256 + threadIdx.x;
  int n = idx >> 10;
  int k = idx & 1023;
  float v = (k < HD) ? Wih[n * HD + k] : Whh[n * HD + (k - HD)];
  Wc[idx] = f2bf(v);
}

__global__ void prep_bias(const float* __restrict__ a, const float* __restrict__ b,
                          float* __restrict__ o){
  int i = blockIdx.x * 256 + threadIdx.x;
  if (i < 2048) o[i] = a[i] + b[i];
}

// Xp[t][row][k] bf16: row<64: text[row][t][k]; row>=64: text[row-64][TS-1-t][k]
__global__ void pack_x(const float* __restrict__ text, unsigned short* __restrict__ Xp){
  int idx = blockIdx.x * 256 + threadIdx.x;   // TS*MBR*HD = 16,777,216
  int k   = idx & 511;
  int row = (idx >> 9) & 127;
  int t   = idx >> 16;
  int b   = row & 63;
  int tt  = (row < 64) ? t : (TS - 1 - t);
  Xp[idx] = f2bf(text[((size_t)b * TS + tt) * HD + k]);
}

// Persistent pipelined 2-layer LSTM, flag-based dataflow sync (no contended RMW).
// Grid: 256 WGs x 512 threads, 1 WG/CU, 128 KB LDS.
// WG wg: layer = wg>>7; wl = wg&127; grp = wl>>5 (32 batch rows); slice = wl&31 (16 units).
// Flags F[0..127]: L0 (grp*32+slice) = completed t+1.  F[128..255]: same for L1.
// L0 step t: wait(F0g>=t, F1g>=t-15 ring backpressure) -> recurrence half ->
//            cell -> store h0[t] -> release flag -> prefetch Xp[t+1] projection.
// L1 step t: wait(F1g>=t) -> recurrence half -> cell -> store h1[t] -> release flag
//            -> wait(F0g>=t+2) -> prefetch h0[t+1]@Wih1.
__global__ __launch_bounds__(512, 1)
void lstm_persist(const unsigned short* __restrict__ Xp,
                  const unsigned short* __restrict__ Wc,   // [2][2048][1024] bf16
                  const float* __restrict__ bias,          // [2][2048]
                  unsigned short* __restrict__ h0r,        // [16][128][512] bf16 ring
                  unsigned short* __restrict__ h1r,        // [2][128][512] bf16 ring
                  float* __restrict__ H1f,                 // [128][512] fp32 (final h1)
                  int* __restrict__ F)                     // [256] flags
{
  extern __shared__ unsigned short Blds[];   // 64 cols x 1024 k, XOR-swizzled, 128 KB

  const int wg    = blockIdx.x;
  const int layer = wg >> 7;
  const int wl    = wg & 127;
  const int grp   = wl >> 5;
  const int slice = wl & 31;
  const int m0    = grp * 32;
  const int u0    = slice * 16;
  const int tid   = threadIdx.x;
  const int wv    = tid >> 6;
  const int l     = tid & 63;
  const int lj    = l & 15;
  const int lk    = l >> 4;
  const int wgrp  = wv & 3;
  const int mi    = wv >> 2;

  int* F0g = F + grp * 32;          // producer flags: layer 0, this row-group
  int* F1g = F + 128 + grp * 32;    // producer flags: layer 1, this row-group

  // ---- one-time: stage this WG's weight slice into LDS, swizzled ----
  const unsigned short* Wcl = Wc + (size_t)layer * 2048 * 1024;
  for (int it = tid; it < 64 * 128; it += 512){
    int c  = it >> 7, kg = it & 127;
    int unit = u0 + ((c >> 4) << 2) + ((c & 15) >> 2);
    int gate = c & 3;
    bf16x8 v = *(const bf16x8*)(Wcl + (size_t)(gate * HD + unit) * 1024 + kg * 8);
    *(bf16x8*)((char*)Blds + c * 2048 + ((kg ^ (c & 7)) << 4)) = v;
  }

  const int myunit = u0 + (wgrp << 2) + (lj >> 2);
  const int mygate = lj & 3;
  const float bgv  = bias[layer * 2048 + mygate * HD + myunit];
  const int aoff   = (m0 + mi * 16 + lj) * HD + lk * 8;
  const int cboff  = (wgrp * 16 + lj) * 2048;
  const int swz    = lj & 7;

  float cst[4] = {0.f, 0.f, 0.f, 0.f};
  __syncthreads();   // weights staged

  // 16-MFMA half-K: gb=0 -> input-side weights, gb=64 -> recurrent weights
  auto halfK = [&](const unsigned short* __restrict__ src, int gb, f32x4& acc){
    #pragma unroll
    for (int kk = 0; kk < 16; ++kk){
      bf16x8 b = *(const bf16x8*)((const char*)Blds + cboff + (((gb + kk * 4 + lk) ^ swz) << 4));
      bf16x8 a = *(const bf16x8*)(src + aoff + kk * 32);
      acc = __builtin_amdgcn_mfma_f32_16x16x32_bf16(a, b, acc, 0, 0, 0);
    }
  };

  // wave-0 poll: lanes 0..31 watch setA>=tA; lanes 32..63 watch setB>=tB (setB may repeat setA)
  auto pollwait = [&](const int* setA, int tA, const int* setB, int tB){
    const int* fp = (l < 32) ? (setA + l) : (setB + (l - 32));
    const int tgt = (l < 32) ? tA : tB;
    for (;;){
      int v = __hip_atomic_load(fp, __ATOMIC_RELAXED, __HIP_MEMORY_SCOPE_AGENT);
      if (__all(v >= tgt)) break;
      __builtin_amdgcn_s_sleep(1);
    }
    __builtin_amdgcn_fence(__ATOMIC_ACQUIRE, "agent");
  };

  auto cellstore = [&](const f32x4& aP, const f32x4& aQ,
                       unsigned short* __restrict__ hout, bool wrF){
    #pragma unroll
    for (int r = 0; r < 4; ++r){
      float v  = aP[r] + aQ[r] + bgv;
      float v1 = __shfl_xor(v, 1);
      float v2 = __shfl_xor(v, 2);
      float v3 = __shfl_xor(v, 3);
      auto pick = [&](int m)->float {
        return m == 0 ? v : (m == 1 ? v1 : (m == 2 ? v2 : v3));
      };
      float gi = pick(mygate);
      float gf = pick(mygate ^ 1);
      float gg = pick(mygate ^ 2);
      float go = pick(mygate ^ 3);
      float i_ = fsig(gi);
      float f_ = fsig(gf);
      float g_ = ftanh(gg);
      float o_ = fsig(go);
      float c  = f_ * cst[r] + i_ * g_;
      cst[r] = c;
      float h = o_ * ftanh(c);
      if (mygate == 0){
        int row = m0 + mi * 16 + lk * 4 + r;
        hout[(size_t)row * HD + myunit] = f2bf(h);
        if (wrF) H1f[(size_t)row * HD + myunit] = h;
      }
    }
  };

  if (layer == 0){
    f32x4 accPre = {0.f, 0.f, 0.f, 0.f};
    halfK(Xp, 0, accPre);                       // x_0 projection
    for (int t = 0; t < TS; ++t){
      if (t > 0){
        if (wv == 0) pollwait(F0g, t, F1g, t - 15);   // peers done t-1; ring slot free
        __syncthreads();
      }
      f32x4 accPost = {0.f, 0.f, 0.f, 0.f};
      if (t > 0) halfK(h0r + (size_t)((t - 1) & 15) * SLAB, 64, accPost);
      cellstore(accPre, accPost, h0r + (size_t)(t & 15) * SLAB, false);
      __syncthreads();                          // drain all waves' h stores
      if (tid == 0)
        __hip_atomic_store(F0g + slice, t + 1, __ATOMIC_RELEASE, __HIP_MEMORY_SCOPE_AGENT);
      if (t + 1 < TS){
        accPre = (f32x4){0.f, 0.f, 0.f, 0.f};
        halfK(Xp + (size_t)(t + 1) * SLAB, 0, accPre);   // overlaps straggler window
      }
    }
  } else {
    if (wv == 0) pollwait(F0g, 1, F0g, 1);      // h0[0] available
    __syncthreads();
    f32x4 accPre = {0.f, 0.f, 0.f, 0.f};
    halfK(h0r, 0, accPre);                      // h0[0] @ Wih1
    for (int t = 0; t < TS; ++t){
      if (t > 0){
        if (wv == 0) pollwait(F1g, t, F1g, t);  // peers done t-1
        __syncthreads();
      }
      f32x4 accPost = {0.f, 0.f, 0.f, 0.f};
      if (t > 0) halfK(h1r + (size_t)((t - 1) & 1) * SLAB, 64, accPost);
      cellstore(accPre, accPost, h1r + (size_t)(t & 1) * SLAB, t == TS - 1);
      __syncthreads();
      if (tid == 0)
        __hip_atomic_store(F1g + slice, t + 1, __ATOMIC_RELEASE, __HIP_MEMORY_SCOPE_AGENT);
      if (t + 1 < TS){
        if (wv == 0) pollwait(F0g, t + 2, F0g, t + 2);   // h0[t+1] available (L0 runs ahead)
        __syncthreads();
        accPre = (f32x4){0.f, 0.f, 0.f, 0.f};
        halfK(h0r + (size_t)((t + 1) & 15) * SLAB, 0, accPre);
      }
    }
  }
}

// out[b] = dot(h1_fwd[b], Wlin[0:512]) + dot(h1_rev[b], Wlin[512:1024]) + blin
__global__ void final_linear(const float* __restrict__ H1f, const float* __restrict__ Wlin,
                             const float* __restrict__ blin, float* __restrict__ out){
  int b = blockIdx.x, l = threadIdx.x;
  float s = 0.f;
  for (int j = l; j < HD; j += 64) s += H1f[(size_t)b * HD + j]        * Wlin[j];
  for (int j = l; j < HD; j += 64) s += H1f[(size_t)(NB + b) * HD + j] * Wlin[HD + j];
  #pragma unroll
  for (int off = 32; off; off >>= 1) s += __shfl_down(s, off);
  if (l == 0) out[b] = s + blin[0];
}

extern "C" void kernel_launch(void* const* d_in, const int* in_sizes, int n_in,
                              void* d_out, int out_size, void* d_ws, size_t ws_size,
                              hipStream_t stream)
{
  const float* text = (const float*)d_in[0];
  const float* Wih0 = (const float*)d_in[1];
  const float* Whh0 = (const float*)d_in[2];
  const float* bih0 = (const float*)d_in[3];
  const float* bhh0 = (const float*)d_in[4];
  const float* Wih1 = (const float*)d_in[5];
  const float* Whh1 = (const float*)d_in[6];
  const float* bih1 = (const float*)d_in[7];
  const float* bhh1 = (const float*)d_in[8];
  const float* Wlin = (const float*)d_in[9];
  const float* blin = (const float*)d_in[10];

  // ---- ws layout (~43 MiB) ----
  uint8_t* p = (uint8_t*)d_ws;
  unsigned short* Wc  = (unsigned short*)p; p += (size_t)2 * 2048 * 1024 * 2;  // 8 MiB
  float* bias         = (float*)p;          p += (size_t)2 * 2048 * 4;         // 16 KiB
  unsigned short* Xp  = (unsigned short*)p; p += (size_t)TS * SLAB * 2;        // 32 MiB
  unsigned short* h0r = (unsigned short*)p; p += (size_t)16 * SLAB * 2;        // 2 MiB ring
  unsigned short* h1r = (unsigned short*)p; p += (size_t)2 * SLAB * 2;         // 256 KiB ring
  float* H1f          = (float*)p;          p += (size_t)SLAB * 4;             // 256 KiB
  int* F              = (int*)p;            p += (size_t)256 * 4;              // 1 KiB flags

  // deterministic init every call: flags MUST be zero at kernel start
  hipMemsetAsync(F, 0, 256 * 4, stream);

  prep_w<<<8192, 256, 0, stream>>>(Wih0, Whh0, Wc);
  prep_w<<<8192, 256, 0, stream>>>(Wih1, Whh1, Wc + (size_t)2048 * 1024);
  prep_bias<<<8, 256, 0, stream>>>(bih0, bhh0, bias);
  prep_bias<<<8, 256, 0, stream>>>(bih1, bhh1, bias + 2048);
  pack_x<<<65536, 256, 0, stream>>>(text, Xp);

  hipFuncSetAttribute((const void*)lstm_persist,
                      hipFuncAttributeMaxDynamicSharedMemorySize, 131072);

  const unsigned short* XpA = Xp;
  const unsigned short* WcA = Wc;
  const float* biasA = bias;
  unsigned short* h0A = h0r;
  unsigned short* h1A = h1r;
  float* H1fA = H1f;
  int* FA = F;
  void* args[] = {(void*)&XpA, (void*)&WcA, (void*)&biasA,
                  (void*)&h0A, (void*)&h1A, (void*)&H1fA, (void*)&FA};
  hipLaunchCooperativeKernel((void*)lstm_persist, dim3(256), dim3(512),
                             args, 131072, stream);

  final_linear<<<NB, 64, 0, stream>>>(H1f, Wlin, blin, (float*)d_out);
}